// Round 13
// baseline (166.440 us; speedup 1.0000x reference)
//
#include <hip/hip_runtime.h>
#include <math.h>

#define TT 8
#define NN 10000
#define EE 32768
#define CC 40
#define EPSV 1e-05f

constexpr float INV3 = 0.57735026918962576f;
constexpr float INV6 = 0.40824829046386302f;
constexpr float N0F  = 0.22360679774997896f;
constexpr float N1OF = 0.22360679774997896f;
constexpr float N1EF = 0.5f;

constexpr float CTab[8] = {1.f, 0.70710678118654752f, 0.f, -0.70710678118654752f,
                           -1.f, -0.70710678118654752f, 0.f, 0.70710678118654752f};
constexpr float STab[8] = {0.f, 0.70710678118654752f, 1.f, 0.70710678118654752f,
                           0.f, -0.70710678118654752f, -1.f, -0.70710678118654752f};

typedef __attribute__((ext_vector_type(8))) short short8;
typedef __attribute__((ext_vector_type(4))) float f32x4;

__device__ __forceinline__ void atomAdd(float* p, float v) {
  __hip_atomic_fetch_add(p, v, __ATOMIC_RELAXED, __HIP_MEMORY_SCOPE_AGENT);
}

__device__ __forceinline__ short f2bfs(float f) {
  unsigned u = __builtin_bit_cast(unsigned, f);
  u = (u + 0x7fffu + ((u >> 16) & 1u)) >> 16;
  return (short)u;
}
__device__ __forceinline__ float bf2f(ushort u) {
  unsigned v = ((unsigned)u) << 16;
  return __builtin_bit_cast(float, v);
}

// ---- fused pre-pass: scanbucket (block 0) | spec (1..157) | prep (158..273) ----
#define SPEC_B 157
#define PREP_B 116
__global__ __launch_bounds__(256) void k_pre(const float* __restrict__ x,
                                             const float* __restrict__ wr,
                                             const float* __restrict__ wi,
                                             const int* __restrict__ ei,
                                             const float* __restrict__ W1,
                                             const float* __restrict__ W2,
                                             float* __restrict__ xsc,
                                             short* __restrict__ W1F,
                                             short* __restrict__ W2F,
                                             int* __restrict__ row_start,
                                             int* __restrict__ ipos,
                                             float* __restrict__ stats) {
  __shared__ int lcnt[NN];   // 40 KB, used by block 0 only
  __shared__ int wtot[4];
  __shared__ int wpre[4];
  int b = blockIdx.x, tid = threadIdx.x;
  if (b == 0) {
    // ---- deg + scan + bucket, 256 threads ----
    if (tid < 80) stats[tid] = 0.f;
    for (int i = tid; i < NN; i += 256) lcnt[i] = 0;
    __syncthreads();
    for (int it = 0; it < EE / 256; ++it) {
      int e = it * 256 + tid;
      atomicAdd(&lcnt[ei[EE + e]], 1);
    }
    __syncthreads();
    const int PER = 40;  // 256*40 >= NN
    int base = tid * PER;
    int s = 0;
    for (int i = 0; i < PER; ++i) {
      int idx = base + i;
      if (idx < NN) s += lcnt[idx];
    }
    int incl = s;
    int lane = tid & 63, wid = tid >> 6;
#pragma unroll
    for (int off = 1; off < 64; off <<= 1) {
      int v = __shfl_up(incl, off);
      if (lane >= off) incl += v;
    }
    if (lane == 63) wtot[wid] = incl;
    __syncthreads();
    if (tid == 0) {
      int run = 0;
#pragma unroll
      for (int i = 0; i < 4; ++i) { wpre[i] = run; run += wtot[i]; }
    }
    __syncthreads();
    int run = wpre[wid] + (incl - s);
    for (int i = 0; i < PER; ++i) {
      int idx = base + i;
      if (idx < NN) {
        int d = lcnt[idx];
        row_start[idx] = run;
        lcnt[idx] = run;   // becomes cursor
        run += d;
      }
    }
    if (tid == 0) row_start[NN] = EE;
    __syncthreads();
    for (int it = 0; it < EE / 256; ++it) {
      int e = it * 256 + tid;
      int d = ei[EE + e];
      int slot = atomicAdd(&lcnt[d], 1);
      ipos[e] = slot;
    }
  } else if (b <= SPEC_B) {
    int gid = (b - 1) * 256 + tid;
    int n = gid >> 2, og = gid & 3;
    if (n >= NN) return;
    float F0[16], A[16], B[16];
#pragma unroll
    for (int i = 0; i < 16; ++i) { F0[i] = 0.f; A[i] = 0.f; B[i] = 0.f; }
#pragma unroll
    for (int t = 0; t < 8; ++t) {
      const float4* xp = (const float4*)(x + ((size_t)t * NN + n) * 28);
      float4 v0 = xp[0], v1 = xp[1], v2 = xp[2], v3 = xp[3];
      const float ct = CTab[t], st = STab[t];
      float vv[16] = {v0.x, v0.y, v0.z, v0.w, v1.x, v1.y, v1.z, v1.w,
                      v2.x, v2.y, v2.z, v2.w, v3.x, v3.y, v3.z, v3.w};
#pragma unroll
      for (int i = 0; i < 16; ++i) {
        F0[i] += vv[i];
        A[i] = fmaf(vv[i], ct, A[i]);
        B[i] = fmaf(vv[i], -st, B[i]);
      }
    }
#pragma unroll
    for (int oo = 0; oo < 4; ++oo) {
      int o = og * 4 + oo;
      float r0 = 0.f, r1 = 0.f, i1 = 0.f;
#pragma unroll
      for (int i = 0; i < 16; ++i) {
        float wr0 = wr[i * 32 + o * 2 + 0];
        float wr1 = wr[i * 32 + o * 2 + 1];
        float wi1 = wi[i * 32 + o * 2 + 1];
        r0 = fmaf(F0[i], wr0, r0);
        r1 += A[i] * wr1 - B[i] * wi1;
        i1 += A[i] * wi1 + B[i] * wr1;
      }
#pragma unroll
      for (int t = 0; t < 8; ++t) {
        float val = 0.125f * (r0 + 2.f * (r1 * CTab[t] - i1 * STab[t]));
        xsc[((size_t)t * NN + n) * 16 + o] = val;
      }
    }
  } else {
    int idx = (b - 1 - SPEC_B) * 256 + tid;
    const int tot1 = 3 * 2 * 64 * 8;
    if (idx < tot1) {
      int elem = idx & 7, lane = (idx >> 3) & 63, kt = (idx >> 9) & 1, nt = idx >> 10;
      int j = kt * 32 + ((lane >> 4) << 2) + (elem & 3) + ((elem >> 2) << 4);
      int n = nt * 16 + (lane & 15);
      W1F[idx] = (j < 48) ? f2bfs(W1[j * 48 + n]) : (short)0;
    } else {
      int id2 = idx - tot1;
      int elem = id2 & 7, lane = (id2 >> 3) & 63, kt = (id2 >> 9) & 1, ck = id2 >> 10;
      int j = kt * 32 + ((lane >> 4) << 2) + (elem & 3) + ((elem >> 2) << 4);
      int n = ck * 16 + (lane & 15);
      W2F[id2] = (j < 48) ? f2bfs(W2[j * 416 + n]) : (short)0;
    }
  }
}

// ---- fused MFMA edge kernel, 2 tiles/wave (32 edges), 128-thread blocks ----
// Each B-fragment load feeds both tiles: W2F L2 traffic halves vs 1-tile.
__global__ __launch_bounds__(128, 3) void k_edge2t(
    const float* __restrict__ x,     // (T,N,28)
    const int* __restrict__ ei,      // (2,E)
    const float* __restrict__ eag,   // (T,E,48)
    const float* __restrict__ shg,   // (T,E,4)
    const short* __restrict__ W1F,
    const short* __restrict__ W2F,
    const float* __restrict__ b1,
    const float* __restrict__ b2,
    const int* __restrict__ ipos,    // edge -> CSR slot
    ushort* __restrict__ msg)        // (T,slot,40) bf16
{
  __shared__ float cSs[16][64];   // s_i*sh0*N0F
  __shared__ float rawSs[16][64]; // s_i
  __shared__ float cVDs[4][64];   // vd_i*N0F
  __shared__ float vS0s[12][64];  // v_i[d]*sh0*INV3*N1OF
  __shared__ float sh1fs[3][64];  // sh1[d]*INV3*N1OF
  __shared__ float cCRs[12][64];  // cross(v_i,sh1)[d]*INV6*N1EF
  __shared__ int   iposs[64];
  __shared__ ushort Hs[2][2][16][64];  // [wave][tile][m][col^swz]

  int blk = blockIdx.x;
  int t = blk >> 9;
  int e0 = (blk & 511) * 64;
  int tid = threadIdx.x;

  // ---- distributed staging: 128 threads, 2 roles over 64 edges ----
  {
    int e = tid & 63;
    int role = tid >> 6;
    int eg = e0 + e;
    const float* shp = shg + ((size_t)t * EE + eg) * 4;
    float sh0 = shp[0], s1x = shp[1], s1y = shp[2], s1z = shp[3];
    int src = ei[eg];
    const float* xr = x + ((size_t)t * NN + src) * 28;
    const float F1 = INV3 * N1OF;
    if (role == 0) {
      iposs[e] = ipos[eg];
      sh1fs[0][e] = s1x * F1; sh1fs[1][e] = s1y * F1; sh1fs[2][e] = s1z * F1;
#pragma unroll
      for (int i = 0; i < 16; ++i) {
        float s = xr[i];
        rawSs[i][e] = s;
        cSs[i][e] = s * sh0 * N0F;
      }
    } else {
#pragma unroll
      for (int i = 0; i < 4; ++i) {
        float vx = xr[16 + 3 * i], vy = xr[17 + 3 * i], vz = xr[18 + 3 * i];
        cVDs[i][e] = (vx * s1x + vy * s1y + vz * s1z) * INV3 * N0F;
        vS0s[3 * i + 0][e] = vx * sh0 * F1;
        vS0s[3 * i + 1][e] = vy * sh0 * F1;
        vS0s[3 * i + 2][e] = vz * sh0 * F1;
        cCRs[3 * i + 0][e] = (vy * s1z - vz * s1y) * INV6 * N1EF;
        cCRs[3 * i + 1][e] = (vz * s1x - vx * s1z) * INV6 * N1EF;
        cCRs[3 * i + 2][e] = (vx * s1y - vy * s1x) * INV6 * N1EF;
      }
    }
  }
  __syncthreads();

  int w = tid >> 6, l = tid & 63;
  int col = l & 15;
  int kq  = (l >> 4) << 2;
  int ebA = w * 32;        // tile 0 base (block-local edge)
  int ebB = w * 32 + 16;   // tile 1 base

  // ---- GEMM1 for both tiles ----
  const float* rowA = eag + ((size_t)t * EE + e0 + ebA + col) * 48;
  const float* rowB = eag + ((size_t)t * EE + e0 + ebB + col) * 48;
  float4 fa = *(const float4*)(rowA + kq);
  float4 fb = *(const float4*)(rowA + 16 + kq);
  float4 fc = *(const float4*)(rowA + 32 + kq);
  float4 ga = *(const float4*)(rowB + kq);
  float4 gb = *(const float4*)(rowB + 16 + kq);
  float4 gc = *(const float4*)(rowB + 32 + kq);
  short8 a0A, a1A, a0B, a1B;
  a0A[0] = f2bfs(fa.x); a0A[1] = f2bfs(fa.y); a0A[2] = f2bfs(fa.z); a0A[3] = f2bfs(fa.w);
  a0A[4] = f2bfs(fb.x); a0A[5] = f2bfs(fb.y); a0A[6] = f2bfs(fb.z); a0A[7] = f2bfs(fb.w);
  a1A[0] = f2bfs(fc.x); a1A[1] = f2bfs(fc.y); a1A[2] = f2bfs(fc.z); a1A[3] = f2bfs(fc.w);
  a1A[4] = 0; a1A[5] = 0; a1A[6] = 0; a1A[7] = 0;
  a0B[0] = f2bfs(ga.x); a0B[1] = f2bfs(ga.y); a0B[2] = f2bfs(ga.z); a0B[3] = f2bfs(ga.w);
  a0B[4] = f2bfs(gb.x); a0B[5] = f2bfs(gb.y); a0B[6] = f2bfs(gb.z); a0B[7] = f2bfs(gb.w);
  a1B[0] = f2bfs(gc.x); a1B[1] = f2bfs(gc.y); a1B[2] = f2bfs(gc.z); a1B[3] = f2bfs(gc.w);
  a1B[4] = 0; a1B[5] = 0; a1B[6] = 0; a1B[7] = 0;

  const short8* w1f = (const short8*)W1F;
  const short8* w2f = (const short8*)W2F;

#pragma unroll
  for (int nt = 0; nt < 3; ++nt) {
    float bias = b1[nt * 16 + col];
    short8 wb0 = w1f[(nt * 2 + 0) * 64 + l];
    short8 wb1 = w1f[(nt * 2 + 1) * 64 + l];
    f32x4 cA = {bias, bias, bias, bias};
    cA = __builtin_amdgcn_mfma_f32_16x16x32_bf16(a0A, wb0, cA, 0, 0, 0);
    cA = __builtin_amdgcn_mfma_f32_16x16x32_bf16(a1A, wb1, cA, 0, 0, 0);
    f32x4 cB = {bias, bias, bias, bias};
    cB = __builtin_amdgcn_mfma_f32_16x16x32_bf16(a0B, wb0, cB, 0, 0, 0);
    cB = __builtin_amdgcn_mfma_f32_16x16x32_bf16(a1B, wb1, cB, 0, 0, 0);
#pragma unroll
    for (int r = 0; r < 4; ++r) {
      int m = kq + r;
      int cidx = (nt * 16 + col) ^ ((m & 7) << 3);
      Hs[w][0][m][cidx] = (ushort)f2bfs(fmaxf(cA[r], 0.f));
      Hs[w][1][m][cidx] = (ushort)f2bfs(fmaxf(cB[r], 0.f));
    }
  }
#pragma unroll
  for (int r = 0; r < 4; ++r) {
    int m = kq + r;
    int cidx = (48 + col) ^ ((m & 7) << 3);
    Hs[w][0][m][cidx] = 0;
    Hs[w][1][m][cidx] = 0;
  }

  // ---- read A-fragments of H for both tiles ----
  int m2 = col, X = (m2 & 7) << 3;
  short8 A20A, A21A, A20B, A21B;
  {
    ushort4 r0 = *(const ushort4*)&Hs[w][0][m2][(kq +  0) ^ X];
    ushort4 r1 = *(const ushort4*)&Hs[w][0][m2][(kq + 16) ^ X];
    ushort4 r2 = *(const ushort4*)&Hs[w][0][m2][(kq + 32) ^ X];
    ushort4 r3 = *(const ushort4*)&Hs[w][0][m2][(kq + 48) ^ X];
    A20A[0] = (short)r0.x; A20A[1] = (short)r0.y; A20A[2] = (short)r0.z; A20A[3] = (short)r0.w;
    A20A[4] = (short)r1.x; A20A[5] = (short)r1.y; A20A[6] = (short)r1.z; A20A[7] = (short)r1.w;
    A21A[0] = (short)r2.x; A21A[1] = (short)r2.y; A21A[2] = (short)r2.z; A21A[3] = (short)r2.w;
    A21A[4] = (short)r3.x; A21A[5] = (short)r3.y; A21A[6] = (short)r3.z; A21A[7] = (short)r3.w;
  }
  {
    ushort4 r0 = *(const ushort4*)&Hs[w][1][m2][(kq +  0) ^ X];
    ushort4 r1 = *(const ushort4*)&Hs[w][1][m2][(kq + 16) ^ X];
    ushort4 r2 = *(const ushort4*)&Hs[w][1][m2][(kq + 32) ^ X];
    ushort4 r3 = *(const ushort4*)&Hs[w][1][m2][(kq + 48) ^ X];
    A20B[0] = (short)r0.x; A20B[1] = (short)r0.y; A20B[2] = (short)r0.z; A20B[3] = (short)r0.w;
    A20B[4] = (short)r1.x; A20B[5] = (short)r1.y; A20B[6] = (short)r1.z; A20B[7] = (short)r1.w;
    A21B[0] = (short)r2.x; A21B[1] = (short)r2.y; A21B[2] = (short)r2.z; A21B[3] = (short)r2.w;
    A21B[4] = (short)r3.x; A21B[5] = (short)r3.y; A21B[6] = (short)r3.z; A21B[7] = (short)r3.w;
  }

  // ---- GEMM2: 26 chunks, each B-frag feeds both tiles ----
  float acc0[2][4]  = {{0.f,0.f,0.f,0.f},{0.f,0.f,0.f,0.f}};
  float accP2[2][4] = {{0.f,0.f,0.f,0.f},{0.f,0.f,0.f,0.f}};
  float acc1o[2][3][4] = {{{0.f,0.f,0.f,0.f},{0.f,0.f,0.f,0.f},{0.f,0.f,0.f,0.f}},
                          {{0.f,0.f,0.f,0.f},{0.f,0.f,0.f,0.f},{0.f,0.f,0.f,0.f}}};
  float acc1e[2][3][4] = {{{0.f,0.f,0.f,0.f},{0.f,0.f,0.f,0.f},{0.f,0.f,0.f,0.f}},
                          {{0.f,0.f,0.f,0.f},{0.f,0.f,0.f,0.f},{0.f,0.f,0.f,0.f}}};
  int er[2] = {ebA + kq, ebB + kq};
  int iloc = col >> 2;
  int o = col & 3;

  short8 pf0[4], pf1[4];
#pragma unroll
  for (int i = 0; i < 4; ++i) {
    pf0[i] = w2f[(2 * i + 0) * 64 + l];
    pf1[i] = w2f[(2 * i + 1) * 64 + l];
  }

#pragma unroll
  for (int ck = 0; ck < 26; ++ck) {
    short8 B0 = pf0[ck & 3], B1 = pf1[ck & 3];
    if (ck + 4 < 26) {
      pf0[ck & 3] = w2f[(2 * (ck + 4) + 0) * 64 + l];
      pf1[ck & 3] = w2f[(2 * (ck + 4) + 1) * 64 + l];
    }
    float bias = b2[ck * 16 + col];
    f32x4 cc0 = {bias, bias, bias, bias};
    cc0 = __builtin_amdgcn_mfma_f32_16x16x32_bf16(A20A, B0, cc0, 0, 0, 0);
    cc0 = __builtin_amdgcn_mfma_f32_16x16x32_bf16(A21A, B1, cc0, 0, 0, 0);
    f32x4 cc1 = {bias, bias, bias, bias};
    cc1 = __builtin_amdgcn_mfma_f32_16x16x32_bf16(A20B, B0, cc1, 0, 0, 0);
    cc1 = __builtin_amdgcn_mfma_f32_16x16x32_bf16(A21B, B1, cc1, 0, 0, 0);
    f32x4 cc[2] = {cc0, cc1};

#pragma unroll
    for (int tb = 0; tb < 2; ++tb) {
      if (ck < 16) {
#pragma unroll
        for (int r = 0; r < 4; ++r)
          acc0[tb][r] = fmaf(cSs[ck][er[tb] + r], cc[tb][r], acc0[tb][r]);
      } else if (ck < 20) {
#pragma unroll
        for (int r = 0; r < 4; ++r) {
          float q = rawSs[(ck - 16) * 4 + iloc][er[tb] + r] * cc[tb][r];
          q += __shfl_xor(q, 4);
          q += __shfl_xor(q, 8);
          accP2[tb][r] += q;
        }
      } else if (ck == 20) {
#pragma unroll
        for (int d = 0; d < 3; ++d)
#pragma unroll
          for (int r = 0; r < 4; ++r) {
            float q = vS0s[iloc * 3 + d][er[tb] + r] * cc[tb][r];
            q += __shfl_xor(q, 4);
            q += __shfl_xor(q, 8);
            acc1o[tb][d][r] += q;
          }
      } else if (ck < 25) {
#pragma unroll
        for (int r = 0; r < 4; ++r)
          acc0[tb][r] = fmaf(cVDs[ck - 21][er[tb] + r], cc[tb][r], acc0[tb][r]);
      } else {
#pragma unroll
        for (int d = 0; d < 3; ++d)
#pragma unroll
          for (int r = 0; r < 4; ++r) {
            float q = cCRs[iloc * 3 + d][er[tb] + r] * cc[tb][r];
            q += __shfl_xor(q, 4);
            q += __shfl_xor(q, 8);
            acc1e[tb][d][r] += q;
          }
      }
    }
  }

  // ---- dense stores at CSR slot ----
#pragma unroll
  for (int tb = 0; tb < 2; ++tb) {
#pragma unroll
    for (int r = 0; r < 4; ++r) {
      size_t eg = (size_t)t * EE + iposs[er[tb] + r];
      msg[eg * 40 + col] = (ushort)f2bfs(acc0[tb][r]);
    }
  }
  if (col < 4) {
#pragma unroll
    for (int tb = 0; tb < 2; ++tb) {
#pragma unroll
      for (int r = 0; r < 4; ++r) {
        int e = er[tb] + r;
        size_t eg = (size_t)t * EE + iposs[e];
        ushort* mrow = msg + eg * 40;
#pragma unroll
        for (int d = 0; d < 3; ++d) {
          mrow[16 + 3 * o + d] = (ushort)f2bfs(fmaf(accP2[tb][r], sh1fs[d][e], acc1o[tb][d][r]));
          mrow[28 + 3 * o + d] = (ushort)f2bfs(acc1e[tb][d][r]);
        }
      }
    }
  }
}

// ---------------- fused gather (sequential rows) + mean + xsc + BN-stats ----------------
__global__ __launch_bounds__(320) void k_gstats(const ushort* __restrict__ msg,
                                                const int* __restrict__ row_start,
                                                const float* __restrict__ xsc,
                                                float* __restrict__ out,
                                                float* __restrict__ stats) {
  int blk = blockIdx.x;           // t*157 + nb
  int t = blk / 157;
  int nb = blk - t * 157;
  int tid = threadIdx.x;
  int g = tid / 40, c = tid - g * 40;
  int r5 = c % 5;
  __shared__ float sred[10];
  if (tid < 10) sred[tid] = 0.f;
  __syncthreads();
  float p = 0.f, q = 0.f;
  for (int step = 0; step < 8; ++step) {
    int n = nb * 64 + step * 8 + g;
    if (n < NN) {
      int a = row_start[n], b = row_start[n + 1];
      float acc = 0.f;
      for (int j = a; j < b; ++j)
        acc += bf2f(msg[((size_t)t * EE + j) * 40 + c]);
      float y = acc / fmaxf((float)(b - a), 1.f) +
                (c < 16 ? xsc[((size_t)t * NN + n) * 16 + c] : 0.f);
      out[((size_t)t * NN + n) * 40 + c] = y;
      p += y;
      q = fmaf(y, y, q);
    }
  }
  atomicAdd(&sred[r5], p);
  atomicAdd(&sred[5 + r5], q);
  __syncthreads();
  if (tid < 10) {
    int r = tid % 5;
    int j = 8 * r + t;
    atomAdd(stats + (tid >= 5 ? 40 + j : j), sred[tid]);
  }
}

// ---------------- normalize (float4, in place) ----------------
__global__ __launch_bounds__(256) void k_norm(const float* __restrict__ stats,
                                              const float* __restrict__ gam,
                                              const float* __restrict__ bet,
                                              float* __restrict__ out) {
  int idx4 = blockIdx.x * 256 + threadIdx.x;
  if (idx4 >= TT * NN * 10) return;
  int t = idx4 / (NN * 10);
  int rem = idx4 - t * NN * 10;
  int c0 = (rem % 10) * 4;
  const float inv = 1.f / (8.f * (float)NN);
  float4* op = (float4*)out;
  float4 y = op[idx4];
  float vals[4] = {y.x, y.y, y.z, y.w};
#pragma unroll
  for (int k = 0; k < 4; ++k) {
    int c = c0 + k;
    int j = 8 * (c % 5) + t;
    float mu = stats[j] * inv;
    float var = stats[40 + j] * inv - mu * mu;
    vals[k] = (vals[k] - mu) * rsqrtf(var + EPSV) * gam[j] + bet[j];
  }
  y.x = vals[0]; y.y = vals[1]; y.z = vals[2]; y.w = vals[3];
  op[idx4] = y;
}

extern "C" void kernel_launch(void* const* d_in, const int* in_sizes, int n_in,
                              void* d_out, int out_size, void* d_ws, size_t ws_size,
                              hipStream_t stream) {
  const float* x   = (const float*)d_in[0];
  const int*   ei  = (const int*)d_in[1];
  const float* ea  = (const float*)d_in[2];
  const float* esh = (const float*)d_in[3];
  const float* W1  = (const float*)d_in[4];
  const float* b1  = (const float*)d_in[5];
  const float* W2  = (const float*)d_in[6];
  const float* b2  = (const float*)d_in[7];
  const float* wr  = (const float*)d_in[8];
  const float* wi  = (const float*)d_in[9];
  const float* gam = (const float*)d_in[10];
  const float* bet = (const float*)d_in[11];
  float* out = (float*)d_out;

  float*  xsc       = (float*)d_ws;                       // 1,280,000 f
  ushort* W1F       = (ushort*)(xsc + 1280000);           // 3,072
  ushort* W2F       = W1F + 3072;                         // 26,624
  ushort* msg       = W2F + 26624;                        // 10,485,760
  float*  stats     = (float*)(msg + (size_t)10485760);   // 80
  int*    row_start = (int*)(stats + 80);                 // 10,001
  int*    ipos      = row_start + 10001;                  // 32,768

  k_pre<<<1 + SPEC_B + PREP_B, 256, 0, stream>>>(x, wr, wi, ei, W1, W2, xsc,
                                                 (short*)W1F, (short*)W2F,
                                                 row_start, ipos, stats);
  k_edge2t<<<TT * (EE / 64), 128, 0, stream>>>(x, ei, ea, esh, (short*)W1F, (short*)W2F,
                                               b1, b2, ipos, msg);
  k_gstats<<<TT * 157, 320, 0, stream>>>(msg, row_start, xsc, out, stats);
  k_norm<<<(TT * NN * 10 + 255) / 256, 256, 0, stream>>>(stats, gam, bet, out);
}

// Round 14
// 151.019 us; speedup vs baseline: 1.1021x; 1.1021x over previous
//
#include <hip/hip_runtime.h>
#include <math.h>

#define TT 8
#define NN 10000
#define EE 32768
#define CC 40
#define EPSV 1e-05f

constexpr float INV3 = 0.57735026918962576f;
constexpr float INV6 = 0.40824829046386302f;
constexpr float N0F  = 0.22360679774997896f;
constexpr float N1OF = 0.22360679774997896f;
constexpr float N1EF = 0.5f;

constexpr float CTab[8] = {1.f, 0.70710678118654752f, 0.f, -0.70710678118654752f,
                           -1.f, -0.70710678118654752f, 0.f, 0.70710678118654752f};
constexpr float STab[8] = {0.f, 0.70710678118654752f, 1.f, 0.70710678118654752f,
                           0.f, -0.70710678118654752f, -1.f, -0.70710678118654752f};

typedef __attribute__((ext_vector_type(8))) short short8;
typedef __attribute__((ext_vector_type(4))) float f32x4;

__device__ __forceinline__ void atomAdd(float* p, float v) {
  __hip_atomic_fetch_add(p, v, __ATOMIC_RELAXED, __HIP_MEMORY_SCOPE_AGENT);
}

__device__ __forceinline__ short f2bfs(float f) {
  unsigned u = __builtin_bit_cast(unsigned, f);
  u = (u + 0x7fffu + ((u >> 16) & 1u)) >> 16;
  return (short)u;
}
__device__ __forceinline__ float bf2f(ushort u) {
  unsigned v = ((unsigned)u) << 16;
  return __builtin_bit_cast(float, v);
}

// ---------------- fused pre-pass: spec (blocks 0..156) | prep (157..272) ----------------
#define SPEC_B 157
#define PREP_B 116
__global__ __launch_bounds__(256) void k_pre(const float* __restrict__ x,
                                             const float* __restrict__ wr,
                                             const float* __restrict__ wi,
                                             const float* __restrict__ W1,
                                             const float* __restrict__ W2,
                                             float* __restrict__ xsc,
                                             short* __restrict__ W1F,
                                             short* __restrict__ W2F) {
  int b = blockIdx.x, tid = threadIdx.x;
  if (b < SPEC_B) {
    int gid = b * 256 + tid;
    int n = gid >> 2, og = gid & 3;
    if (n >= NN) return;
    float F0[16], A[16], B[16];
#pragma unroll
    for (int i = 0; i < 16; ++i) { F0[i] = 0.f; A[i] = 0.f; B[i] = 0.f; }
#pragma unroll
    for (int t = 0; t < 8; ++t) {
      const float4* xp = (const float4*)(x + ((size_t)t * NN + n) * 28);
      float4 v0 = xp[0], v1 = xp[1], v2 = xp[2], v3 = xp[3];
      const float ct = CTab[t], st = STab[t];
      float vv[16] = {v0.x, v0.y, v0.z, v0.w, v1.x, v1.y, v1.z, v1.w,
                      v2.x, v2.y, v2.z, v2.w, v3.x, v3.y, v3.z, v3.w};
#pragma unroll
      for (int i = 0; i < 16; ++i) {
        F0[i] += vv[i];
        A[i] = fmaf(vv[i], ct, A[i]);
        B[i] = fmaf(vv[i], -st, B[i]);
      }
    }
#pragma unroll
    for (int oo = 0; oo < 4; ++oo) {
      int o = og * 4 + oo;
      float r0 = 0.f, r1 = 0.f, i1 = 0.f;
#pragma unroll
      for (int i = 0; i < 16; ++i) {
        float wr0 = wr[i * 32 + o * 2 + 0];
        float wr1 = wr[i * 32 + o * 2 + 1];
        float wi1 = wi[i * 32 + o * 2 + 1];
        r0 = fmaf(F0[i], wr0, r0);
        r1 += A[i] * wr1 - B[i] * wi1;
        i1 += A[i] * wi1 + B[i] * wr1;
      }
#pragma unroll
      for (int t = 0; t < 8; ++t) {
        float val = 0.125f * (r0 + 2.f * (r1 * CTab[t] - i1 * STab[t]));
        xsc[((size_t)t * NN + n) * 16 + o] = val;
      }
    }
  } else {
    int idx = (b - SPEC_B) * 256 + tid;
    const int tot1 = 3 * 2 * 64 * 8;
    if (idx < tot1) {
      int elem = idx & 7, lane = (idx >> 3) & 63, kt = (idx >> 9) & 1, nt = idx >> 10;
      int j = kt * 32 + ((lane >> 4) << 2) + (elem & 3) + ((elem >> 2) << 4);
      int n = nt * 16 + (lane & 15);
      W1F[idx] = (j < 48) ? f2bfs(W1[j * 48 + n]) : (short)0;
    } else {
      int id2 = idx - tot1;
      int elem = id2 & 7, lane = (id2 >> 3) & 63, kt = (id2 >> 9) & 1, ck = id2 >> 10;
      int j = kt * 32 + ((lane >> 4) << 2) + (elem & 3) + ((elem >> 2) << 4);
      int n = ck * 16 + (lane & 15);
      W2F[id2] = (j < 48) ? f2bfs(W2[j * 416 + n]) : (short)0;
    }
  }
}

// ---------------- single-block deg + scan + bucket (1024 thr, LDS) ----------------
__global__ __launch_bounds__(1024) void k_scanbucket(const int* __restrict__ ei,
                                                     int* __restrict__ row_start,
                                                     int* __restrict__ ipos,
                                                     float* __restrict__ stats) {
  __shared__ int lcnt[NN];
  __shared__ int wtot[16];
  __shared__ int wpre[16];
  int tid = threadIdx.x;
  if (tid < 80) stats[tid] = 0.f;
  for (int i = tid; i < NN; i += 1024) lcnt[i] = 0;
  __syncthreads();
#pragma unroll
  for (int it = 0; it < EE / 1024; ++it) {
    int e = it * 1024 + tid;
    atomicAdd(&lcnt[ei[EE + e]], 1);
  }
  __syncthreads();
  const int PER = 10;
  int base = tid * PER;
  int s = 0;
  if (base < NN) {
#pragma unroll
    for (int i = 0; i < PER; ++i) s += lcnt[base + i];
  }
  int incl = s;
  int lane = tid & 63, wid = tid >> 6;
#pragma unroll
  for (int off = 1; off < 64; off <<= 1) {
    int v = __shfl_up(incl, off);
    if (lane >= off) incl += v;
  }
  if (lane == 63) wtot[wid] = incl;
  __syncthreads();
  if (tid == 0) {
    int run = 0;
#pragma unroll
    for (int i = 0; i < 16; ++i) { wpre[i] = run; run += wtot[i]; }
  }
  __syncthreads();
  int run = wpre[wid] + (incl - s);
  if (base < NN) {
#pragma unroll
    for (int i = 0; i < PER; ++i) {
      int n = base + i;
      int d = lcnt[n];
      row_start[n] = run;
      lcnt[n] = run;
      run += d;
    }
  }
  if (tid == 0) row_start[NN] = EE;
  __syncthreads();
#pragma unroll
  for (int it = 0; it < EE / 1024; ++it) {
    int e = it * 1024 + tid;
    int d = ei[EE + e];
    int slot = atomicAdd(&lcnt[d], 1);
    ipos[e] = slot;
  }
}

// ---------------- fused MFMA edge kernel: W2F staged in LDS (2 halves) ----------------
// vs round-12: pf0/pf1 runtime-indexed "prefetch" arrays DELETED (rule #20 — they were
// scratch/demoted); B-fragments now come from a block-shared LDS copy of W2F staged in
// two 26.6 KB halves (per-block L2 traffic instead of per-wave; ds_read latency ~120cy).
__global__ __launch_bounds__(256, 4) void k_edge5(
    const float* __restrict__ x,     // (T,N,28)
    const int* __restrict__ ei,      // (2,E)
    const float* __restrict__ eag,   // (T,E,48)
    const float* __restrict__ shg,   // (T,E,4)
    const short* __restrict__ W1F,
    const short* __restrict__ W2F,
    const float* __restrict__ b1,
    const float* __restrict__ b2,
    const int* __restrict__ ipos,    // edge -> CSR slot
    ushort* __restrict__ msg)        // (T,slot,40) bf16
{
  __shared__ float cSs[16][64];
  __shared__ float rawSs[16][64];
  __shared__ float cVDs[4][64];
  __shared__ float vS0s[12][64];
  __shared__ float sh1fs[3][64];
  __shared__ float cCRs[12][64];
  __shared__ int   iposs[64];
  __shared__ ushort Hs[4][16][64];
  __shared__ short8 w2s[26][64];   // 26.6 KB: half of W2F fragment rows

  int blk = blockIdx.x;
  int t = blk >> 9;
  int e0 = (blk & 511) * 64;
  int tid = threadIdx.x;
  int w = tid >> 6, l = tid & 63;

  const short8* w1f = (const short8*)W1F;
  const short8* w2f = (const short8*)W2F;

  // ---- distributed coefficient staging (as round 12) ----
  {
    int e = tid & 63;
    int role = tid >> 6;
    int eg = e0 + e;
    const float* shp = shg + ((size_t)t * EE + eg) * 4;
    float sh0 = shp[0], s1x = shp[1], s1y = shp[2], s1z = shp[3];
    int src = ei[eg];
    const float* xr = x + ((size_t)t * NN + src) * 28;
    const float F1 = INV3 * N1OF;
    if (role == 0) {
      iposs[e] = ipos[eg];
      sh1fs[0][e] = s1x * F1; sh1fs[1][e] = s1y * F1; sh1fs[2][e] = s1z * F1;
#pragma unroll
      for (int i = 0; i < 8; ++i) {
        float s = xr[i];
        rawSs[i][e] = s;
        cSs[i][e] = s * sh0 * N0F;
      }
    } else if (role == 1) {
#pragma unroll
      for (int i = 8; i < 16; ++i) {
        float s = xr[i];
        rawSs[i][e] = s;
        cSs[i][e] = s * sh0 * N0F;
      }
    } else {
      int i0 = (role == 2) ? 0 : 2;
#pragma unroll
      for (int ii = 0; ii < 2; ++ii) {
        int i = i0 + ii;
        float vx = xr[16 + 3 * i], vy = xr[17 + 3 * i], vz = xr[18 + 3 * i];
        cVDs[i][e] = (vx * s1x + vy * s1y + vz * s1z) * INV3 * N0F;
        vS0s[3 * i + 0][e] = vx * sh0 * F1;
        vS0s[3 * i + 1][e] = vy * sh0 * F1;
        vS0s[3 * i + 2][e] = vz * sh0 * F1;
        cCRs[3 * i + 0][e] = (vy * s1z - vz * s1y) * INV6 * N1EF;
        cCRs[3 * i + 1][e] = (vz * s1x - vx * s1z) * INV6 * N1EF;
        cCRs[3 * i + 2][e] = (vx * s1y - vy * s1x) * INV6 * N1EF;
      }
    }
  }
  // ---- stage W2F half 0 (fragment rows 0..25) ----
  for (int r = w; r < 26; r += 4) w2s[r][l] = w2f[r * 64 + l];
  __syncthreads();

  int col = l & 15;
  int kq  = (l >> 4) << 2;
  int eb  = w * 16;

  // ---- GEMM1: H = relu(EA @ W1 + b1) ----
  const float* row = eag + ((size_t)t * EE + e0 + eb + col) * 48;
  float4 fa = *(const float4*)(row + kq);
  float4 fb = *(const float4*)(row + 16 + kq);
  float4 fc = *(const float4*)(row + 32 + kq);
  short8 a0, a1;
  a0[0] = f2bfs(fa.x); a0[1] = f2bfs(fa.y); a0[2] = f2bfs(fa.z); a0[3] = f2bfs(fa.w);
  a0[4] = f2bfs(fb.x); a0[5] = f2bfs(fb.y); a0[6] = f2bfs(fb.z); a0[7] = f2bfs(fb.w);
  a1[0] = f2bfs(fc.x); a1[1] = f2bfs(fc.y); a1[2] = f2bfs(fc.z); a1[3] = f2bfs(fc.w);
  a1[4] = 0; a1[5] = 0; a1[6] = 0; a1[7] = 0;

#pragma unroll
  for (int nt = 0; nt < 3; ++nt) {
    float bias = b1[nt * 16 + col];
    f32x4 c = {bias, bias, bias, bias};
    c = __builtin_amdgcn_mfma_f32_16x16x32_bf16(a0, w1f[(nt * 2 + 0) * 64 + l], c, 0, 0, 0);
    c = __builtin_amdgcn_mfma_f32_16x16x32_bf16(a1, w1f[(nt * 2 + 1) * 64 + l], c, 0, 0, 0);
#pragma unroll
    for (int r = 0; r < 4; ++r) {
      int m = kq + r;
      float hv = fmaxf(c[r], 0.f);
      Hs[w][m][(nt * 16 + col) ^ ((m & 7) << 3)] = (ushort)f2bfs(hv);
    }
  }
#pragma unroll
  for (int r = 0; r < 4; ++r) {
    int m = kq + r;
    Hs[w][m][(48 + col) ^ ((m & 7) << 3)] = 0;
  }

  // ---- read A-fragments of H (wave-private) ----
  int m2 = col, X = (m2 & 7) << 3;
  ushort4 r0 = *(const ushort4*)&Hs[w][m2][(kq +  0) ^ X];
  ushort4 r1 = *(const ushort4*)&Hs[w][m2][(kq + 16) ^ X];
  ushort4 r2 = *(const ushort4*)&Hs[w][m2][(kq + 32) ^ X];
  ushort4 r3 = *(const ushort4*)&Hs[w][m2][(kq + 48) ^ X];
  short8 A20, A21;
  A20[0] = (short)r0.x; A20[1] = (short)r0.y; A20[2] = (short)r0.z; A20[3] = (short)r0.w;
  A20[4] = (short)r1.x; A20[5] = (short)r1.y; A20[6] = (short)r1.z; A20[7] = (short)r1.w;
  A21[0] = (short)r2.x; A21[1] = (short)r2.y; A21[2] = (short)r2.z; A21[3] = (short)r2.w;
  A21[4] = (short)r3.x; A21[5] = (short)r3.y; A21[6] = (short)r3.z; A21[7] = (short)r3.w;

  // ---- GEMM2: 26 chunks in two LDS-staged halves ----
  float acc0[4]  = {0.f, 0.f, 0.f, 0.f};
  float accP2[4] = {0.f, 0.f, 0.f, 0.f};
  float acc1o[3][4] = {{0.f,0.f,0.f,0.f},{0.f,0.f,0.f,0.f},{0.f,0.f,0.f,0.f}};
  float acc1e[3][4] = {{0.f,0.f,0.f,0.f},{0.f,0.f,0.f,0.f},{0.f,0.f,0.f,0.f}};
  int er0 = eb + kq;
  int iloc = col >> 2;
  int o = col & 3;

  auto body = [&](int ck, short8 B0, short8 B1) {
    float bias = b2[ck * 16 + col];
    f32x4 c = {bias, bias, bias, bias};
    c = __builtin_amdgcn_mfma_f32_16x16x32_bf16(A20, B0, c, 0, 0, 0);
    c = __builtin_amdgcn_mfma_f32_16x16x32_bf16(A21, B1, c, 0, 0, 0);

    if (ck < 16) {
      float4 cv = *(const float4*)&cSs[ck][er0];
      float cvr[4] = {cv.x, cv.y, cv.z, cv.w};
#pragma unroll
      for (int r = 0; r < 4; ++r)
        acc0[r] = fmaf(cvr[r], c[r], acc0[r]);
    } else if (ck < 20) {
      float4 cv = *(const float4*)&rawSs[(ck - 16) * 4 + iloc][er0];
      float cvr[4] = {cv.x, cv.y, cv.z, cv.w};
#pragma unroll
      for (int r = 0; r < 4; ++r) {
        float q = cvr[r] * c[r];
        q += __shfl_xor(q, 4);
        q += __shfl_xor(q, 8);
        accP2[r] += q;
      }
    } else if (ck == 20) {
#pragma unroll
      for (int d = 0; d < 3; ++d) {
        float4 cv = *(const float4*)&vS0s[iloc * 3 + d][er0];
        float cvr[4] = {cv.x, cv.y, cv.z, cv.w};
#pragma unroll
        for (int r = 0; r < 4; ++r) {
          float q = cvr[r] * c[r];
          q += __shfl_xor(q, 4);
          q += __shfl_xor(q, 8);
          acc1o[d][r] += q;
        }
      }
    } else if (ck < 25) {
      float4 cv = *(const float4*)&cVDs[ck - 21][er0];
      float cvr[4] = {cv.x, cv.y, cv.z, cv.w};
#pragma unroll
      for (int r = 0; r < 4; ++r)
        acc0[r] = fmaf(cvr[r], c[r], acc0[r]);
    } else {
#pragma unroll
      for (int d = 0; d < 3; ++d) {
        float4 cv = *(const float4*)&cCRs[iloc * 3 + d][er0];
        float cvr[4] = {cv.x, cv.y, cv.z, cv.w};
#pragma unroll
        for (int r = 0; r < 4; ++r) {
          float q = cvr[r] * c[r];
          q += __shfl_xor(q, 4);
          q += __shfl_xor(q, 8);
          acc1e[d][r] += q;
        }
      }
    }
  };

#pragma unroll
  for (int ck = 0; ck < 13; ++ck)
    body(ck, w2s[2 * ck][l], w2s[2 * ck + 1][l]);

  __syncthreads();   // all waves done with half 0
  for (int r = w; r < 26; r += 4) w2s[r][l] = w2f[(26 + r) * 64 + l];
  __syncthreads();   // half 1 staged

#pragma unroll
  for (int ck = 13; ck < 26; ++ck)
    body(ck, w2s[2 * (ck - 13)][l], w2s[2 * (ck - 13) + 1][l]);

  // ---- dense stores at CSR slot ----
#pragma unroll
  for (int r = 0; r < 4; ++r) {
    size_t eg = (size_t)t * EE + iposs[er0 + r];
    msg[eg * 40 + col] = (ushort)f2bfs(acc0[r]);
  }
  if (col < 4) {
    float4 s0 = *(const float4*)&sh1fs[0][er0];
    float4 s1 = *(const float4*)&sh1fs[1][er0];
    float4 s2 = *(const float4*)&sh1fs[2][er0];
    float sh1v[3][4] = {{s0.x, s0.y, s0.z, s0.w},
                        {s1.x, s1.y, s1.z, s1.w},
                        {s2.x, s2.y, s2.z, s2.w}};
#pragma unroll
    for (int r = 0; r < 4; ++r) {
      size_t eg = (size_t)t * EE + iposs[er0 + r];
      ushort* mrow = msg + eg * 40;
#pragma unroll
      for (int d = 0; d < 3; ++d) {
        mrow[16 + 3 * o + d] = (ushort)f2bfs(fmaf(accP2[r], sh1v[d][r], acc1o[d][r]));
        mrow[28 + 3 * o + d] = (ushort)f2bfs(acc1e[d][r]);
      }
    }
  }
}

// ---------------- fused gather (sequential rows) + mean + xsc + BN-stats ----------------
__global__ __launch_bounds__(320) void k_gstats(const ushort* __restrict__ msg,
                                                const int* __restrict__ row_start,
                                                const float* __restrict__ xsc,
                                                float* __restrict__ out,
                                                float* __restrict__ stats) {
  int blk = blockIdx.x;           // t*157 + nb
  int t = blk / 157;
  int nb = blk - t * 157;
  int tid = threadIdx.x;
  int g = tid / 40, c = tid - g * 40;
  int r5 = c % 5;
  __shared__ float sred[10];
  if (tid < 10) sred[tid] = 0.f;
  __syncthreads();
  float p = 0.f, q = 0.f;
  for (int step = 0; step < 8; ++step) {
    int n = nb * 64 + step * 8 + g;
    if (n < NN) {
      int a = row_start[n], b = row_start[n + 1];
      float acc = 0.f;
      for (int j = a; j < b; ++j)
        acc += bf2f(msg[((size_t)t * EE + j) * 40 + c]);
      float y = acc / fmaxf((float)(b - a), 1.f) +
                (c < 16 ? xsc[((size_t)t * NN + n) * 16 + c] : 0.f);
      out[((size_t)t * NN + n) * 40 + c] = y;
      p += y;
      q = fmaf(y, y, q);
    }
  }
  atomicAdd(&sred[r5], p);
  atomicAdd(&sred[5 + r5], q);
  __syncthreads();
  if (tid < 10) {
    int r = tid % 5;
    int j = 8 * r + t;
    atomAdd(stats + (tid >= 5 ? 40 + j : j), sred[tid]);
  }
}

// ---------------- normalize (float4, in place) ----------------
__global__ __launch_bounds__(256) void k_norm(const float* __restrict__ stats,
                                              const float* __restrict__ gam,
                                              const float* __restrict__ bet,
                                              float* __restrict__ out) {
  int idx4 = blockIdx.x * 256 + threadIdx.x;
  if (idx4 >= TT * NN * 10) return;
  int t = idx4 / (NN * 10);
  int rem = idx4 - t * NN * 10;
  int c0 = (rem % 10) * 4;
  const float inv = 1.f / (8.f * (float)NN);
  float4* op = (float4*)out;
  float4 y = op[idx4];
  float vals[4] = {y.x, y.y, y.z, y.w};
#pragma unroll
  for (int k = 0; k < 4; ++k) {
    int c = c0 + k;
    int j = 8 * (c % 5) + t;
    float mu = stats[j] * inv;
    float var = stats[40 + j] * inv - mu * mu;
    vals[k] = (vals[k] - mu) * rsqrtf(var + EPSV) * gam[j] + bet[j];
  }
  y.x = vals[0]; y.y = vals[1]; y.z = vals[2]; y.w = vals[3];
  op[idx4] = y;
}

extern "C" void kernel_launch(void* const* d_in, const int* in_sizes, int n_in,
                              void* d_out, int out_size, void* d_ws, size_t ws_size,
                              hipStream_t stream) {
  const float* x   = (const float*)d_in[0];
  const int*   ei  = (const int*)d_in[1];
  const float* ea  = (const float*)d_in[2];
  const float* esh = (const float*)d_in[3];
  const float* W1  = (const float*)d_in[4];
  const float* b1  = (const float*)d_in[5];
  const float* W2  = (const float*)d_in[6];
  const float* b2  = (const float*)d_in[7];
  const float* wr  = (const float*)d_in[8];
  const float* wi  = (const float*)d_in[9];
  const float* gam = (const float*)d_in[10];
  const float* bet = (const float*)d_in[11];
  float* out = (float*)d_out;

  float*  xsc       = (float*)d_ws;                       // 1,280,000 f
  ushort* W1F       = (ushort*)(xsc + 1280000);           // 3,072
  ushort* W2F       = W1F + 3072;                         // 26,624
  ushort* msg       = W2F + 26624;                        // 10,485,760
  float*  stats     = (float*)(msg + (size_t)10485760);   // 80
  int*    row_start = (int*)(stats + 80);                 // 10,001
  int*    ipos      = row_start + 10001;                  // 32,768

  k_pre<<<SPEC_B + PREP_B, 256, 0, stream>>>(x, wr, wi, W1, W2, xsc,
                                             (short*)W1F, (short*)W2F);
  k_scanbucket<<<1, 1024, 0, stream>>>(ei, row_start, ipos, stats);
  k_edge5<<<TT * (EE / 64), 256, 0, stream>>>(x, ei, ea, esh, (short*)W1F, (short*)W2F,
                                              b1, b2, ipos, msg);
  k_gstats<<<TT * 157, 320, 0, stream>>>(msg, row_start, xsc, out, stats);
  k_norm<<<(TT * NN * 10 + 255) / 256, 256, 0, stream>>>(stats, gam, bet, out);
}

// Round 15
// 141.176 us; speedup vs baseline: 1.1790x; 1.0697x over previous
//
#include <hip/hip_runtime.h>
#include <math.h>

#define TT 8
#define NN 10000
#define EE 32768
#define CC 40
#define EPSV 1e-05f

constexpr float INV3 = 0.57735026918962576f;
constexpr float INV6 = 0.40824829046386302f;
constexpr float N0F  = 0.22360679774997896f;
constexpr float N1OF = 0.22360679774997896f;
constexpr float N1EF = 0.5f;

constexpr float CTab[8] = {1.f, 0.70710678118654752f, 0.f, -0.70710678118654752f,
                           -1.f, -0.70710678118654752f, 0.f, 0.70710678118654752f};
constexpr float STab[8] = {0.f, 0.70710678118654752f, 1.f, 0.70710678118654752f,
                           0.f, -0.70710678118654752f, -1.f, -0.70710678118654752f};

typedef __attribute__((ext_vector_type(8))) short short8;
typedef __attribute__((ext_vector_type(4))) float f32x4;

__device__ __forceinline__ void atomAdd(float* p, float v) {
  __hip_atomic_fetch_add(p, v, __ATOMIC_RELAXED, __HIP_MEMORY_SCOPE_AGENT);
}

__device__ __forceinline__ short f2bfs(float f) {
  unsigned u = __builtin_bit_cast(unsigned, f);
  u = (u + 0x7fffu + ((u >> 16) & 1u)) >> 16;
  return (short)u;
}
__device__ __forceinline__ float bf2f(ushort u) {
  unsigned v = ((unsigned)u) << 16;
  return __builtin_bit_cast(float, v);
}

// ---- fused pre-pass: spec (0..156) | prep (157..272) | deg (273..304, int4-batched) ----
#define SPEC_B 157
#define PREP_B 116
#define DEG_B  32
__global__ __launch_bounds__(256) void k_pre(const float* __restrict__ x,
                                             const float* __restrict__ wr,
                                             const float* __restrict__ wi,
                                             const int* __restrict__ ei,
                                             const float* __restrict__ W1,
                                             const float* __restrict__ W2,
                                             float* __restrict__ xsc,
                                             short* __restrict__ W1F,
                                             short* __restrict__ W2F,
                                             int* __restrict__ deg) {
  int b = blockIdx.x, tid = threadIdx.x;
  if (b < SPEC_B) {
    int gid = b * 256 + tid;
    int n = gid >> 2, og = gid & 3;
    if (n >= NN) return;
    float F0[16], A[16], B[16];
#pragma unroll
    for (int i = 0; i < 16; ++i) { F0[i] = 0.f; A[i] = 0.f; B[i] = 0.f; }
#pragma unroll
    for (int t = 0; t < 8; ++t) {
      const float4* xp = (const float4*)(x + ((size_t)t * NN + n) * 28);
      float4 v0 = xp[0], v1 = xp[1], v2 = xp[2], v3 = xp[3];
      const float ct = CTab[t], st = STab[t];
      float vv[16] = {v0.x, v0.y, v0.z, v0.w, v1.x, v1.y, v1.z, v1.w,
                      v2.x, v2.y, v2.z, v2.w, v3.x, v3.y, v3.z, v3.w};
#pragma unroll
      for (int i = 0; i < 16; ++i) {
        F0[i] += vv[i];
        A[i] = fmaf(vv[i], ct, A[i]);
        B[i] = fmaf(vv[i], -st, B[i]);
      }
    }
#pragma unroll
    for (int oo = 0; oo < 4; ++oo) {
      int o = og * 4 + oo;
      float r0 = 0.f, r1 = 0.f, i1 = 0.f;
#pragma unroll
      for (int i = 0; i < 16; ++i) {
        float wr0 = wr[i * 32 + o * 2 + 0];
        float wr1 = wr[i * 32 + o * 2 + 1];
        float wi1 = wi[i * 32 + o * 2 + 1];
        r0 = fmaf(F0[i], wr0, r0);
        r1 += A[i] * wr1 - B[i] * wi1;
        i1 += A[i] * wi1 + B[i] * wr1;
      }
#pragma unroll
      for (int t = 0; t < 8; ++t) {
        float val = 0.125f * (r0 + 2.f * (r1 * CTab[t] - i1 * STab[t]));
        xsc[((size_t)t * NN + n) * 16 + o] = val;
      }
    }
  } else if (b < SPEC_B + PREP_B) {
    int idx = (b - SPEC_B) * 256 + tid;
    const int tot1 = 3 * 2 * 64 * 8;
    if (idx < tot1) {
      int elem = idx & 7, lane = (idx >> 3) & 63, kt = (idx >> 9) & 1, nt = idx >> 10;
      int j = kt * 32 + ((lane >> 4) << 2) + (elem & 3) + ((elem >> 2) << 4);
      int n = nt * 16 + (lane & 15);
      W1F[idx] = (j < 48) ? f2bfs(W1[j * 48 + n]) : (short)0;
    } else {
      int id2 = idx - tot1;
      int elem = id2 & 7, lane = (id2 >> 3) & 63, kt = (id2 >> 9) & 1, ck = id2 >> 10;
      int j = kt * 32 + ((lane >> 4) << 2) + (elem & 3) + ((elem >> 2) << 4);
      int n = ck * 16 + (lane & 15);
      W2F[id2] = (j < 48) ? f2bfs(W2[j * 416 + n]) : (short)0;
    }
  } else {
    // deg: int4-batched global atomics (no LDS -> no occupancy impact on spec/prep)
    int gid = (b - SPEC_B - PREP_B) * 256 + tid;
    int4 d4 = *(const int4*)&ei[EE + gid * 4];
    atomicAdd(&deg[d4.x], 1);
    atomicAdd(&deg[d4.y], 1);
    atomicAdd(&deg[d4.z], 1);
    atomicAdd(&deg[d4.w], 1);
  }
}

// ---- scan (from global deg) + bucket, 1024 thr, int4-batched bucket loop ----
__global__ __launch_bounds__(1024) void k_scanbucket(const int* __restrict__ ei,
                                                     const int* __restrict__ deg,
                                                     int* __restrict__ row_start,
                                                     int* __restrict__ ipos,
                                                     float* __restrict__ stats) {
  __shared__ int lcnt[NN];   // cursor
  __shared__ int wtot[16];
  __shared__ int wpre[16];
  int tid = threadIdx.x;
  if (tid < 80) stats[tid] = 0.f;
  const int PER = 10;
  int base = tid * PER;
  int d[PER];
  int s = 0;
#pragma unroll
  for (int i = 0; i < PER; ++i) {
    int idx = base + i;
    d[i] = (idx < NN) ? deg[idx] : 0;
    s += d[i];
  }
  int incl = s;
  int lane = tid & 63, wid = tid >> 6;
#pragma unroll
  for (int off = 1; off < 64; off <<= 1) {
    int v = __shfl_up(incl, off);
    if (lane >= off) incl += v;
  }
  if (lane == 63) wtot[wid] = incl;
  __syncthreads();
  if (tid == 0) {
    int run = 0;
#pragma unroll
    for (int i = 0; i < 16; ++i) { wpre[i] = run; run += wtot[i]; }
  }
  __syncthreads();
  int run = wpre[wid] + (incl - s);
#pragma unroll
  for (int i = 0; i < PER; ++i) {
    int idx = base + i;
    if (idx < NN) {
      row_start[idx] = run;
      lcnt[idx] = run;
      run += d[i];
    }
  }
  if (tid == 1023) row_start[NN] = EE;
  __syncthreads();
  // bucket: 4 edges/thread/iter, coalesced int4 load + int4 store
#pragma unroll
  for (int it = 0; it < EE / 4096; ++it) {
    int g = it * 1024 + tid;
    int4 d4 = *(const int4*)&ei[EE + g * 4];
    int4 s4;
    s4.x = atomicAdd(&lcnt[d4.x], 1);
    s4.y = atomicAdd(&lcnt[d4.y], 1);
    s4.z = atomicAdd(&lcnt[d4.z], 1);
    s4.w = atomicAdd(&lcnt[d4.w], 1);
    *(int4*)&ipos[g * 4] = s4;
  }
}

// ---------------- fused MFMA edge kernel [round-12 optimum, verbatim] ----------------
__global__ __launch_bounds__(256, 4) void k_edge4(
    const float* __restrict__ x,     // (T,N,28)
    const int* __restrict__ ei,      // (2,E)
    const float* __restrict__ eag,   // (T,E,48)
    const float* __restrict__ shg,   // (T,E,4)
    const short* __restrict__ W1F,
    const short* __restrict__ W2F,
    const float* __restrict__ b1,
    const float* __restrict__ b2,
    const int* __restrict__ ipos,    // edge -> CSR slot
    ushort* __restrict__ msg)        // (T,slot,40) bf16
{
  __shared__ float cSs[16][64];
  __shared__ float rawSs[16][64];
  __shared__ float cVDs[4][64];
  __shared__ float vS0s[12][64];
  __shared__ float sh1fs[3][64];
  __shared__ float cCRs[12][64];
  __shared__ int   iposs[64];
  __shared__ ushort Hs[4][16][64];

  int blk = blockIdx.x;
  int t = blk >> 9;
  int e0 = (blk & 511) * 64;
  int tid = threadIdx.x;

  {
    int e = tid & 63;
    int role = tid >> 6;
    int eg = e0 + e;
    const float* shp = shg + ((size_t)t * EE + eg) * 4;
    float sh0 = shp[0], s1x = shp[1], s1y = shp[2], s1z = shp[3];
    int src = ei[eg];
    const float* xr = x + ((size_t)t * NN + src) * 28;
    const float F1 = INV3 * N1OF;
    if (role == 0) {
      iposs[e] = ipos[eg];
      sh1fs[0][e] = s1x * F1; sh1fs[1][e] = s1y * F1; sh1fs[2][e] = s1z * F1;
#pragma unroll
      for (int i = 0; i < 8; ++i) {
        float s = xr[i];
        rawSs[i][e] = s;
        cSs[i][e] = s * sh0 * N0F;
      }
    } else if (role == 1) {
#pragma unroll
      for (int i = 8; i < 16; ++i) {
        float s = xr[i];
        rawSs[i][e] = s;
        cSs[i][e] = s * sh0 * N0F;
      }
    } else {
      int i0 = (role == 2) ? 0 : 2;
#pragma unroll
      for (int ii = 0; ii < 2; ++ii) {
        int i = i0 + ii;
        float vx = xr[16 + 3 * i], vy = xr[17 + 3 * i], vz = xr[18 + 3 * i];
        cVDs[i][e] = (vx * s1x + vy * s1y + vz * s1z) * INV3 * N0F;
        vS0s[3 * i + 0][e] = vx * sh0 * F1;
        vS0s[3 * i + 1][e] = vy * sh0 * F1;
        vS0s[3 * i + 2][e] = vz * sh0 * F1;
        cCRs[3 * i + 0][e] = (vy * s1z - vz * s1y) * INV6 * N1EF;
        cCRs[3 * i + 1][e] = (vz * s1x - vx * s1z) * INV6 * N1EF;
        cCRs[3 * i + 2][e] = (vx * s1y - vy * s1x) * INV6 * N1EF;
      }
    }
  }
  __syncthreads();

  int w = tid >> 6, l = tid & 63;
  int col = l & 15;
  int kq  = (l >> 4) << 2;
  int eb  = w * 16;

  const float* row = eag + ((size_t)t * EE + e0 + eb + col) * 48;
  float4 fa = *(const float4*)(row + kq);
  float4 fb = *(const float4*)(row + 16 + kq);
  float4 fc = *(const float4*)(row + 32 + kq);
  short8 a0, a1;
  a0[0] = f2bfs(fa.x); a0[1] = f2bfs(fa.y); a0[2] = f2bfs(fa.z); a0[3] = f2bfs(fa.w);
  a0[4] = f2bfs(fb.x); a0[5] = f2bfs(fb.y); a0[6] = f2bfs(fb.z); a0[7] = f2bfs(fb.w);
  a1[0] = f2bfs(fc.x); a1[1] = f2bfs(fc.y); a1[2] = f2bfs(fc.z); a1[3] = f2bfs(fc.w);
  a1[4] = 0; a1[5] = 0; a1[6] = 0; a1[7] = 0;

  const short8* w1f = (const short8*)W1F;
  const short8* w2f = (const short8*)W2F;

#pragma unroll
  for (int nt = 0; nt < 3; ++nt) {
    float bias = b1[nt * 16 + col];
    f32x4 c = {bias, bias, bias, bias};
    c = __builtin_amdgcn_mfma_f32_16x16x32_bf16(a0, w1f[(nt * 2 + 0) * 64 + l], c, 0, 0, 0);
    c = __builtin_amdgcn_mfma_f32_16x16x32_bf16(a1, w1f[(nt * 2 + 1) * 64 + l], c, 0, 0, 0);
#pragma unroll
    for (int r = 0; r < 4; ++r) {
      int m = kq + r;
      float hv = fmaxf(c[r], 0.f);
      Hs[w][m][(nt * 16 + col) ^ ((m & 7) << 3)] = (ushort)f2bfs(hv);
    }
  }
#pragma unroll
  for (int r = 0; r < 4; ++r) {
    int m = kq + r;
    Hs[w][m][(48 + col) ^ ((m & 7) << 3)] = 0;
  }

  int m2 = col, X = (m2 & 7) << 3;
  ushort4 r0 = *(const ushort4*)&Hs[w][m2][(kq +  0) ^ X];
  ushort4 r1 = *(const ushort4*)&Hs[w][m2][(kq + 16) ^ X];
  ushort4 r2 = *(const ushort4*)&Hs[w][m2][(kq + 32) ^ X];
  ushort4 r3 = *(const ushort4*)&Hs[w][m2][(kq + 48) ^ X];
  short8 A20, A21;
  A20[0] = (short)r0.x; A20[1] = (short)r0.y; A20[2] = (short)r0.z; A20[3] = (short)r0.w;
  A20[4] = (short)r1.x; A20[5] = (short)r1.y; A20[6] = (short)r1.z; A20[7] = (short)r1.w;
  A21[0] = (short)r2.x; A21[1] = (short)r2.y; A21[2] = (short)r2.z; A21[3] = (short)r2.w;
  A21[4] = (short)r3.x; A21[5] = (short)r3.y; A21[6] = (short)r3.z; A21[7] = (short)r3.w;

  float acc0[4]  = {0.f, 0.f, 0.f, 0.f};
  float accP2[4] = {0.f, 0.f, 0.f, 0.f};
  float acc1o[3][4] = {{0.f,0.f,0.f,0.f},{0.f,0.f,0.f,0.f},{0.f,0.f,0.f,0.f}};
  float acc1e[3][4] = {{0.f,0.f,0.f,0.f},{0.f,0.f,0.f,0.f},{0.f,0.f,0.f,0.f}};
  int er0 = eb + kq;
  int iloc = col >> 2;
  int o = col & 3;

  short8 pf0[4], pf1[4];
#pragma unroll
  for (int i = 0; i < 4; ++i) {
    pf0[i] = w2f[(2 * i + 0) * 64 + l];
    pf1[i] = w2f[(2 * i + 1) * 64 + l];
  }

#pragma unroll
  for (int ck = 0; ck < 26; ++ck) {
    short8 B0 = pf0[ck & 3], B1 = pf1[ck & 3];
    if (ck + 4 < 26) {
      pf0[ck & 3] = w2f[(2 * (ck + 4) + 0) * 64 + l];
      pf1[ck & 3] = w2f[(2 * (ck + 4) + 1) * 64 + l];
    }
    float bias = b2[ck * 16 + col];
    f32x4 c = {bias, bias, bias, bias};
    c = __builtin_amdgcn_mfma_f32_16x16x32_bf16(A20, B0, c, 0, 0, 0);
    c = __builtin_amdgcn_mfma_f32_16x16x32_bf16(A21, B1, c, 0, 0, 0);

    if (ck < 16) {
      float4 cv = *(const float4*)&cSs[ck][er0];
      float cvr[4] = {cv.x, cv.y, cv.z, cv.w};
#pragma unroll
      for (int r = 0; r < 4; ++r)
        acc0[r] = fmaf(cvr[r], c[r], acc0[r]);
    } else if (ck < 20) {
      float4 cv = *(const float4*)&rawSs[(ck - 16) * 4 + iloc][er0];
      float cvr[4] = {cv.x, cv.y, cv.z, cv.w};
#pragma unroll
      for (int r = 0; r < 4; ++r) {
        float q = cvr[r] * c[r];
        q += __shfl_xor(q, 4);
        q += __shfl_xor(q, 8);
        accP2[r] += q;
      }
    } else if (ck == 20) {
#pragma unroll
      for (int d = 0; d < 3; ++d) {
        float4 cv = *(const float4*)&vS0s[iloc * 3 + d][er0];
        float cvr[4] = {cv.x, cv.y, cv.z, cv.w};
#pragma unroll
        for (int r = 0; r < 4; ++r) {
          float q = cvr[r] * c[r];
          q += __shfl_xor(q, 4);
          q += __shfl_xor(q, 8);
          acc1o[d][r] += q;
        }
      }
    } else if (ck < 25) {
      float4 cv = *(const float4*)&cVDs[ck - 21][er0];
      float cvr[4] = {cv.x, cv.y, cv.z, cv.w};
#pragma unroll
      for (int r = 0; r < 4; ++r)
        acc0[r] = fmaf(cvr[r], c[r], acc0[r]);
    } else {
#pragma unroll
      for (int d = 0; d < 3; ++d) {
        float4 cv = *(const float4*)&cCRs[iloc * 3 + d][er0];
        float cvr[4] = {cv.x, cv.y, cv.z, cv.w};
#pragma unroll
        for (int r = 0; r < 4; ++r) {
          float q = cvr[r] * c[r];
          q += __shfl_xor(q, 4);
          q += __shfl_xor(q, 8);
          acc1e[d][r] += q;
        }
      }
    }
  }

#pragma unroll
  for (int r = 0; r < 4; ++r) {
    size_t eg = (size_t)t * EE + iposs[er0 + r];
    msg[eg * 40 + col] = (ushort)f2bfs(acc0[r]);
  }
  if (col < 4) {
    float4 s0 = *(const float4*)&sh1fs[0][er0];
    float4 s1 = *(const float4*)&sh1fs[1][er0];
    float4 s2 = *(const float4*)&sh1fs[2][er0];
    float sh1v[3][4] = {{s0.x, s0.y, s0.z, s0.w},
                        {s1.x, s1.y, s1.z, s1.w},
                        {s2.x, s2.y, s2.z, s2.w}};
#pragma unroll
    for (int r = 0; r < 4; ++r) {
      size_t eg = (size_t)t * EE + iposs[er0 + r];
      ushort* mrow = msg + eg * 40;
#pragma unroll
      for (int d = 0; d < 3; ++d) {
        mrow[16 + 3 * o + d] = (ushort)f2bfs(fmaf(accP2[r], sh1v[d][r], acc1o[d][r]));
        mrow[28 + 3 * o + d] = (ushort)f2bfs(acc1e[d][r]);
      }
    }
  }
}

// ---------------- fused gather (sequential rows) + mean + xsc + BN-stats ----------------
__global__ __launch_bounds__(320) void k_gstats(const ushort* __restrict__ msg,
                                                const int* __restrict__ row_start,
                                                const float* __restrict__ xsc,
                                                float* __restrict__ out,
                                                float* __restrict__ stats) {
  int blk = blockIdx.x;           // t*157 + nb
  int t = blk / 157;
  int nb = blk - t * 157;
  int tid = threadIdx.x;
  int g = tid / 40, c = tid - g * 40;
  int r5 = c % 5;
  __shared__ float sred[10];
  if (tid < 10) sred[tid] = 0.f;
  __syncthreads();
  float p = 0.f, q = 0.f;
  for (int step = 0; step < 8; ++step) {
    int n = nb * 64 + step * 8 + g;
    if (n < NN) {
      int a = row_start[n], b = row_start[n + 1];
      float acc = 0.f;
      for (int j = a; j < b; ++j)
        acc += bf2f(msg[((size_t)t * EE + j) * 40 + c]);
      float y = acc / fmaxf((float)(b - a), 1.f) +
                (c < 16 ? xsc[((size_t)t * NN + n) * 16 + c] : 0.f);
      out[((size_t)t * NN + n) * 40 + c] = y;
      p += y;
      q = fmaf(y, y, q);
    }
  }
  atomicAdd(&sred[r5], p);
  atomicAdd(&sred[5 + r5], q);
  __syncthreads();
  if (tid < 10) {
    int r = tid % 5;
    int j = 8 * r + t;
    atomAdd(stats + (tid >= 5 ? 40 + j : j), sred[tid]);
  }
}

// ---------------- normalize (float4, in place) ----------------
__global__ __launch_bounds__(256) void k_norm(const float* __restrict__ stats,
                                              const float* __restrict__ gam,
                                              const float* __restrict__ bet,
                                              float* __restrict__ out) {
  int idx4 = blockIdx.x * 256 + threadIdx.x;
  if (idx4 >= TT * NN * 10) return;
  int t = idx4 / (NN * 10);
  int rem = idx4 - t * NN * 10;
  int c0 = (rem % 10) * 4;
  const float inv = 1.f / (8.f * (float)NN);
  float4* op = (float4*)out;
  float4 y = op[idx4];
  float vals[4] = {y.x, y.y, y.z, y.w};
#pragma unroll
  for (int k = 0; k < 4; ++k) {
    int c = c0 + k;
    int j = 8 * (c % 5) + t;
    float mu = stats[j] * inv;
    float var = stats[40 + j] * inv - mu * mu;
    vals[k] = (vals[k] - mu) * rsqrtf(var + EPSV) * gam[j] + bet[j];
  }
  y.x = vals[0]; y.y = vals[1]; y.z = vals[2]; y.w = vals[3];
  op[idx4] = y;
}

extern "C" void kernel_launch(void* const* d_in, const int* in_sizes, int n_in,
                              void* d_out, int out_size, void* d_ws, size_t ws_size,
                              hipStream_t stream) {
  const float* x   = (const float*)d_in[0];
  const int*   ei  = (const int*)d_in[1];
  const float* ea  = (const float*)d_in[2];
  const float* esh = (const float*)d_in[3];
  const float* W1  = (const float*)d_in[4];
  const float* b1  = (const float*)d_in[5];
  const float* W2  = (const float*)d_in[6];
  const float* b2  = (const float*)d_in[7];
  const float* wr  = (const float*)d_in[8];
  const float* wi  = (const float*)d_in[9];
  const float* gam = (const float*)d_in[10];
  const float* bet = (const float*)d_in[11];
  float* out = (float*)d_out;

  float*  xsc       = (float*)d_ws;                       // 1,280,000 f
  ushort* W1F       = (ushort*)(xsc + 1280000);           // 3,072
  ushort* W2F       = W1F + 3072;                         // 26,624
  ushort* msg       = W2F + 26624;                        // 10,485,760
  float*  stats     = (float*)(msg + (size_t)10485760);   // 80
  int*    row_start = (int*)(stats + 80);                 // 10,004 (padded for alignment)
  int*    ipos      = row_start + 10004;                  // 32,768 (16B-aligned)
  int*    deg       = ipos + 32768;                       // 10,000

  hipMemsetAsync(deg, 0, 10000 * sizeof(int), stream);

  k_pre<<<SPEC_B + PREP_B + DEG_B, 256, 0, stream>>>(x, wr, wi, ei, W1, W2, xsc,
                                                     (short*)W1F, (short*)W2F, deg);
  k_scanbucket<<<1, 1024, 0, stream>>>(ei, deg, row_start, ipos, stats);
  k_edge4<<<TT * (EE / 64), 256, 0, stream>>>(x, ei, ea, esh, (short*)W1F, (short*)W2F,
                                              b1, b2, ipos, msg);
  k_gstats<<<TT * 157, 320, 0, stream>>>(msg, row_start, xsc, out, stats);
  k_norm<<<(TT * NN * 10 + 255) / 256, 256, 0, stream>>>(stats, gam, bet, out);
}